// Round 1
// baseline (174.375 us; speedup 1.0000x reference)
//
#include <hip/hip_runtime.h>
#include <hip/hip_bf16.h>
#include <math.h>

// Problem constants (fixed by the reference's setup_inputs):
//   B=256 batch, N=8192 sum rows, C=32768 child cols, NSE=524288 edges.
// rows[] is sorted and every row in [0,N) appears at least once.
#define BB   256
#define NN   8192
#define CC   32768
#define NSE_ 524288

// ---------------------------------------------------------------------------
// Kernel 1: per-edge exp(log_w) and CSR row_start construction from sorted COO
// ---------------------------------------------------------------------------
__global__ __launch_bounds__(256) void prep_kernel(
    const float* __restrict__ lw, const int* __restrict__ rows,
    float* __restrict__ ew, int* __restrict__ rs) {
    int e = blockIdx.x * 256 + threadIdx.x;
    if (e >= NSE_) return;
    ew[e] = __expf(lw[e]);
    if (e == 0) {
        rs[0] = 0;
        rs[NN] = NSE_;
    } else if (rows[e] != rows[e - 1]) {
        // rows sorted + every row present => boundaries land exactly once per row
        rs[rows[e]] = e;
    }
}

// ---------------------------------------------------------------------------
// Kernel 2: fused transpose + exp:  cet[c*B + b] = exp(child_ll[b*C + c])
// Tiled 32x32 through LDS (+1 pad), coalesced both ways.
// ---------------------------------------------------------------------------
__global__ __launch_bounds__(256) void transpose_exp_kernel(
    const float* __restrict__ ll, float* __restrict__ cet) {
    __shared__ float tile[32][33];
    int tx = threadIdx.x & 31;   // 0..31
    int ty = threadIdx.x >> 5;   // 0..7
    int c0 = blockIdx.x * 32;
    int b0 = blockIdx.y * 32;
    #pragma unroll
    for (int k = 0; k < 32; k += 8) {
        int b = b0 + ty + k;
        int c = c0 + tx;
        tile[ty + k][tx] = ll[(size_t)b * CC + c];   // [b_local][c_local]
    }
    __syncthreads();
    #pragma unroll
    for (int k = 0; k < 32; k += 8) {
        int c = c0 + ty + k;
        int b = b0 + tx;
        cet[(size_t)c * BB + b] = __expf(tile[tx][ty + k]);
    }
}

// ---------------------------------------------------------------------------
// Kernel 3: main. One wave per row n. Each lane owns 4 batches (float4),
// so a wave covers all 256 batches of each edge with a fully-used 1KiB gather.
// Per 64-edge window: coalesced prefetch of (col, ew); broadcast each edge
// via v_readlane (scalar col -> saddr global_load_dwordx4); 16-deep unrolled
// chunks give 16 independent gathers in flight.
// ---------------------------------------------------------------------------
__device__ __forceinline__ float readlane_f(float v, int l) {
    return __int_as_float(__builtin_amdgcn_readlane(__float_as_int(v), l));
}

__global__ __launch_bounds__(256) void sum_rows_kernel(
    const int* __restrict__ cols, const float* __restrict__ ew,
    const int* __restrict__ rs, const float* __restrict__ cet,
    float* __restrict__ out) {
    int wave = (blockIdx.x * 256 + threadIdx.x) >> 6;   // global wave id = row
    int lane = threadIdx.x & 63;
    int n = wave;
    if (n >= NN) return;

    // Uniform loop bounds in SGPRs
    int s = __builtin_amdgcn_readfirstlane(rs[n]);
    int t = __builtin_amdgcn_readfirstlane(rs[n + 1]);

    float4 acc = make_float4(0.f, 0.f, 0.f, 0.f);
    float  zs  = 0.f;
    const int voff = lane << 2;     // element offset of this lane's 4 batches

    for (int eb = s; eb < t; eb += 64) {
        int e = eb + lane;
        bool valid = (e < t);
        int   ce = valid ? cols[e] : 0;
        float we = valid ? ew[e]   : 0.f;
        int rem = t - eb; if (rem > 64) rem = 64;

        for (int jj = 0; jj < rem; jj += 16) {
            #pragma unroll
            for (int j2 = 0; j2 < 16; ++j2) {
                int   j = jj + j2;                       // < 64 always
                int   c = __builtin_amdgcn_readlane(ce, j);   // SGPR col
                float w = readlane_f(we, j);                   // SGPR weight
                const float4 g = *reinterpret_cast<const float4*>(
                    &cet[((size_t)c << 8) + voff]);
                acc.x = fmaf(w, g.x, acc.x);
                acc.y = fmaf(w, g.y, acc.y);
                acc.z = fmaf(w, g.z, acc.z);
                acc.w = fmaf(w, g.w, acc.w);
                zs += w;   // padded lanes contribute w=0
            }
        }
    }

    float lz = __logf(zs);
    int b = lane << 2;
    out[(size_t)(b + 0) * NN + n] = __logf(acc.x) - lz;
    out[(size_t)(b + 1) * NN + n] = __logf(acc.y) - lz;
    out[(size_t)(b + 2) * NN + n] = __logf(acc.z) - lz;
    out[(size_t)(b + 3) * NN + n] = __logf(acc.w) - lz;
}

// ---------------------------------------------------------------------------
extern "C" void kernel_launch(void* const* d_in, const int* in_sizes, int n_in,
                              void* d_out, int out_size, void* d_ws, size_t ws_size,
                              hipStream_t stream) {
    const float* child_ll = (const float*)d_in[0];   // [B, C]
    const float* log_w    = (const float*)d_in[1];   // [NSE]
    const int*   rows     = (const int*)  d_in[2];   // [NSE] sorted
    const int*   cols     = (const int*)  d_in[3];   // [NSE]
    float* out = (float*)d_out;                      // [B, N]

    // Workspace layout (needs ~36 MiB):
    //   [0, 2MiB)        ew   : NSE floats
    //   [2MiB, 2MiB+33KB) rs  : N+1 ints
    //   [4MiB, 36MiB)    cet  : C*B floats (transposed exp(child_ll))
    char* ws = (char*)d_ws;
    float* ew  = (float*)(ws);
    int*   rs  = (int*)  (ws + (size_t)2 * 1024 * 1024);
    float* cet = (float*)(ws + (size_t)4 * 1024 * 1024);

    prep_kernel<<<NSE_ / 256, 256, 0, stream>>>(log_w, rows, ew, rs);
    transpose_exp_kernel<<<dim3(CC / 32, BB / 32), 256, 0, stream>>>(child_ll, cet);
    sum_rows_kernel<<<(NN * 64) / 256, 256, 0, stream>>>(cols, ew, rs, cet, out);
}

// Round 2
// 166.306 us; speedup vs baseline: 1.0485x; 1.0485x over previous
//
#include <hip/hip_runtime.h>
#include <hip/hip_bf16.h>

// B=256 batch, N=8192 rows, C=32768 cols, NSE=524288 edges (sorted rows).
#define BB   256
#define NN   8192
#define CC   32768
#define NSE_ 524288
#define GB   32                       // batches per XCD group
#define PREP_BLOCKS (NSE_ / 256)      // 2048
#define TP_BLOCKS   ((CC / 32) * 8)   // 8192

__device__ __forceinline__ unsigned int f2bf_rne(float f) {
    unsigned int u = __float_as_uint(f);
    return (u + 0x7fffu + ((u >> 16) & 1u)) >> 16;   // round-to-nearest-even
}

// ---------------------------------------------------------------------------
// Fused prep (exp(log_w) + CSR row_start) and transpose+exp to bf16 slices:
//   cet[((g*CC + c)*32 + b_local)] = bf16(exp(child_ll[(g*32+b_local)*CC + c]))
// ---------------------------------------------------------------------------
__global__ __launch_bounds__(256) void prep_transpose_kernel(
    const float* __restrict__ lw, const int* __restrict__ rows,
    const float* __restrict__ ll,
    float* __restrict__ ew, int* __restrict__ rs,
    unsigned short* __restrict__ cet) {
    int bid = blockIdx.x;
    if (bid < PREP_BLOCKS) {
        int e = bid * 256 + threadIdx.x;
        ew[e] = __expf(lw[e]);
        if (e == 0) { rs[0] = 0; rs[NN] = NSE_; }
        else if (rows[e] != rows[e - 1]) rs[rows[e]] = e;  // sorted, all rows present
        return;
    }
    bid -= PREP_BLOCKS;
    int g = bid & 7;          // batch group == XCD slice
    int ctile = bid >> 3;
    __shared__ float tile[32][33];
    int tx = threadIdx.x & 31, ty = threadIdx.x >> 5;
    int c0 = ctile * 32, b0 = g * 32;
    #pragma unroll
    for (int k = 0; k < 32; k += 8)
        tile[ty + k][tx] = ll[(size_t)(b0 + ty + k) * CC + (c0 + tx)];
    __syncthreads();
    size_t base = ((size_t)g * CC + c0) * GB;   // in ushort elements
    #pragma unroll
    for (int p = 0; p < 2; ++p) {
        int idx2 = 2 * (int)threadIdx.x + 512 * p;  // even element index in tile
        int cl = idx2 >> 5;        // 0..31 local col
        int bl = idx2 & 31;        // even local batch
        unsigned int lo = f2bf_rne(__expf(tile[bl][cl]));
        unsigned int hi = f2bf_rne(__expf(tile[bl + 1][cl]));
        *reinterpret_cast<unsigned int*>(cet + base + idx2) = lo | (hi << 16);
    }
}

// ---------------------------------------------------------------------------
// Main: wave = (row n, group g). Lane = (grp = lane>>3 edge sub-slot,
// bq = lane&7 batch quad). Per inner step the wave covers 8 edges x 32
// batches; each edge-slice is exactly one 64B line inside this XCD's 2 MiB
// L2-resident slice. cols/ew streamed nontemporal. Cross-grp shfl_xor
// reduction at the end; lanes grp==0 store 32 outputs.
// ---------------------------------------------------------------------------
__global__ __launch_bounds__(256) void sum_rows_kernel(
    const int* __restrict__ cols, const float* __restrict__ ew,
    const int* __restrict__ rs, const unsigned short* __restrict__ cet,
    float* __restrict__ out) {
    __shared__ uint2 stage[4][64];
    int g = blockIdx.x & 7;       // -> XCD via round-robin dispatch
    int nb = blockIdx.x >> 3;
    int wv = threadIdx.x >> 6;
    int lane = threadIdx.x & 63;
    int n = nb * 4 + wv;
    int grp = lane >> 3;
    int bq = lane & 7;
    int s = __builtin_amdgcn_readfirstlane(rs[n]);
    int t = __builtin_amdgcn_readfirstlane(rs[n + 1]);
    const unsigned short* slice = cet + (size_t)g * CC * GB + (bq << 2);
    float4 acc = make_float4(0.f, 0.f, 0.f, 0.f);
    float zs = 0.f;
    uint2* st = stage[wv];

    for (int eb = s; eb < t; eb += 64) {
        int e = eb + lane;
        uint2 cw = make_uint2(0u, 0u);    // col=0 (safe), w=0 (no contribution)
        if (e < t) {
            cw.x = (unsigned)__builtin_nontemporal_load(cols + e);
            cw.y = __float_as_uint(__builtin_nontemporal_load(ew + e));
        }
        st[lane] = cw;                    // wave-private stage, no barrier needed
        #pragma unroll
        for (int j = 0; j < 8; ++j) {
            uint2 p = st[j * 8 + grp];    // broadcast within 8-lane group
            float w = __uint_as_float(p.y);
            uint2 u = *reinterpret_cast<const uint2*>(slice + ((size_t)p.x << 5));
            acc.x = fmaf(w, __uint_as_float(u.x << 16),          acc.x);
            acc.y = fmaf(w, __uint_as_float(u.x & 0xffff0000u), acc.y);
            acc.z = fmaf(w, __uint_as_float(u.y << 16),          acc.z);
            acc.w = fmaf(w, __uint_as_float(u.y & 0xffff0000u), acc.w);
            zs += w;
        }
    }
    #pragma unroll
    for (int off = 8; off < 64; off <<= 1) {   // reduce over grp (bits 3..5)
        acc.x += __shfl_xor(acc.x, off);
        acc.y += __shfl_xor(acc.y, off);
        acc.z += __shfl_xor(acc.z, off);
        acc.w += __shfl_xor(acc.w, off);
        zs    += __shfl_xor(zs, off);
    }
    if (grp == 0) {
        float lz = __logf(zs);
        int b = g * GB + (bq << 2);
        __builtin_nontemporal_store(__logf(acc.x) - lz, out + (size_t)(b + 0) * NN + n);
        __builtin_nontemporal_store(__logf(acc.y) - lz, out + (size_t)(b + 1) * NN + n);
        __builtin_nontemporal_store(__logf(acc.z) - lz, out + (size_t)(b + 2) * NN + n);
        __builtin_nontemporal_store(__logf(acc.w) - lz, out + (size_t)(b + 3) * NN + n);
    }
}

// ---------------------------------------------------------------------------
extern "C" void kernel_launch(void* const* d_in, const int* in_sizes, int n_in,
                              void* d_out, int out_size, void* d_ws, size_t ws_size,
                              hipStream_t stream) {
    const float* child_ll = (const float*)d_in[0];   // [B, C]
    const float* log_w    = (const float*)d_in[1];   // [NSE]
    const int*   rows     = (const int*)  d_in[2];   // [NSE] sorted
    const int*   cols     = (const int*)  d_in[3];   // [NSE]
    float* out = (float*)d_out;                      // [B, N]

    // Workspace: [0,2MiB) ew | [2MiB,+33KB) rs | [4MiB,20MiB) cet (bf16 slices)
    char* ws = (char*)d_ws;
    float*          ew  = (float*)ws;
    int*            rs  = (int*)(ws + (size_t)2 * 1024 * 1024);
    unsigned short* cet = (unsigned short*)(ws + (size_t)4 * 1024 * 1024);

    prep_transpose_kernel<<<PREP_BLOCKS + TP_BLOCKS, 256, 0, stream>>>(
        log_w, rows, child_ll, ew, rs, cet);
    sum_rows_kernel<<<(NN / 4) * 8, 256, 0, stream>>>(cols, ew, rs, cet, out);
}

// Round 3
// 135.428 us; speedup vs baseline: 1.2876x; 1.2280x over previous
//
#include <hip/hip_runtime.h>
#include <hip/hip_bf16.h>

// B=256 batch, N=8192 rows, C=32768 cols, NSE=524288 edges (rows sorted,
// every row present).
#define BB   256
#define NN   8192
#define CC   32768
#define NSE_ 524288
#define GB   32                  // batches per XCD group (8 groups)

__device__ __forceinline__ unsigned int f2bf_rne(float f) {
    unsigned int u = __float_as_uint(f);
    return (u + 0x7fffu + ((u >> 16) & 1u)) >> 16;   // round-to-nearest-even
}

// ---------------------------------------------------------------------------
// Kernel 1: cw[e] = (col[e], exp(log_w[e])) packed uint2, padded with 64
// zero-weight entries; CSR row_start from sorted rows.
// ---------------------------------------------------------------------------
__global__ __launch_bounds__(256) void prep_cw_kernel(
    const float* __restrict__ lw, const int* __restrict__ rows,
    const int* __restrict__ cols, uint2* __restrict__ cw,
    int* __restrict__ rs) {
    int e = blockIdx.x * 256 + threadIdx.x;
    if (e < NSE_) {
        cw[e] = make_uint2((unsigned)cols[e], __float_as_uint(__expf(lw[e])));
        if (e == 0) { rs[0] = 0; rs[NN] = NSE_; }
        else if (rows[e] != rows[e - 1]) rs[rows[e]] = e;
    } else if (e < NSE_ + 64) {
        cw[e] = make_uint2(0u, 0u);     // col=0 (safe), w=0
    }
}

// ---------------------------------------------------------------------------
// Kernel 2: transpose+exp to bf16 XCD slices:
//   cet[g][c][bl] = bf16(exp(child_ll[g*32+bl][c])),  layout [8][CC][32] bf16.
// Block = (64-col tile, g). Reads: 256B contiguous per wave; writes: 4KB
// contiguous per block. LDS tile padded -> conflict-free.
// ---------------------------------------------------------------------------
__global__ __launch_bounds__(256) void transpose_kernel(
    const float* __restrict__ ll, unsigned int* __restrict__ cet32) {
    int g = blockIdx.x & 7;
    int ct = blockIdx.x >> 3;
    int c0 = ct * 64, b0 = g * GB;
    __shared__ float tile[64][33];      // [c_local][b_local]
    int t = threadIdx.x;
    int cl = t & 63, bh = t >> 6;       // bh = 0..3
    #pragma unroll
    for (int k = 0; k < 8; ++k) {
        int bl = bh + 4 * k;            // 0..31
        tile[cl][bl] = ll[(size_t)(b0 + bl) * CC + (c0 + cl)];
    }
    __syncthreads();
    size_t baseu = ((size_t)g * CC + c0) * 16;   // uint index (2 bf16 per uint)
    #pragma unroll
    for (int k = 0; k < 4; ++k) {
        int u = t + 256 * k;            // 0..1023
        int c = u >> 4, b2 = (u & 15) * 2;
        unsigned int lo = f2bf_rne(__expf(tile[c][b2]));
        unsigned int hi = f2bf_rne(__expf(tile[c][b2 + 1]));
        cet32[baseu + u] = lo | (hi << 16);
    }
}

// ---------------------------------------------------------------------------
// Kernel 3: main SpMM-style gather-accumulate.
// Block = (16-row tile, g). 4 waves, each wave 4 rows sequentially.
// Lane = (grp = lane>>2 edge slot 0..15, bq = lane&3 batch octet).
// Per j-slot: broadcast uint2 cw load (4 lanes share) + one uint4 gather
// (4 lanes cover the 64B line of one col in this XCD's 2 MiB slice).
// Epilogue: shfl_xor reduce over grp, LDS-stage 16x32 block outputs,
// fully-coalesced float4 writes (kills the 16x write amplification).
// ---------------------------------------------------------------------------
__global__ __launch_bounds__(256) void sum_rows_kernel(
    const uint2* __restrict__ cw, const int* __restrict__ rs,
    const uint4* __restrict__ cet, float* __restrict__ out) {
    __shared__ float lds_out[32][17];
    int g = blockIdx.x & 7;             // -> XCD round-robin
    int ntile = blockIdx.x >> 3;
    int n0 = ntile * 16;
    int wv = threadIdx.x >> 6;
    int lane = threadIdx.x & 63;
    int grp = lane >> 2;                // 0..15
    int bq = lane & 3;                  // 0..3
    const uint4* slice = cet + (size_t)g * CC * 4;   // 4 uint4 per col

    for (int r = 0; r < 4; ++r) {
        int n = n0 + wv * 4 + r;
        int s = __builtin_amdgcn_readfirstlane(rs[n]);
        int t = __builtin_amdgcn_readfirstlane(rs[n + 1]);
        float acc[8] = {0.f, 0.f, 0.f, 0.f, 0.f, 0.f, 0.f, 0.f};
        float zs = 0.f;
        #pragma unroll 1
        for (int eb = s; eb < t; eb += 64) {
            #pragma unroll
            for (int j = 0; j < 4; ++j) {
                int e = eb + j * 16 + grp;
                uint2 p = cw[e];                        // bcast across 4 bq lanes
                float w = (e < t) ? __uint_as_float(p.y) : 0.f;
                uint4 u = slice[(p.x << 2) | bq];       // one 64B line / 4 lanes
                acc[0] = fmaf(w, __uint_as_float(u.x << 16),          acc[0]);
                acc[1] = fmaf(w, __uint_as_float(u.x & 0xffff0000u), acc[1]);
                acc[2] = fmaf(w, __uint_as_float(u.y << 16),          acc[2]);
                acc[3] = fmaf(w, __uint_as_float(u.y & 0xffff0000u), acc[3]);
                acc[4] = fmaf(w, __uint_as_float(u.z << 16),          acc[4]);
                acc[5] = fmaf(w, __uint_as_float(u.z & 0xffff0000u), acc[5]);
                acc[6] = fmaf(w, __uint_as_float(u.w << 16),          acc[6]);
                acc[7] = fmaf(w, __uint_as_float(u.w & 0xffff0000u), acc[7]);
                zs += w;
            }
        }
        #pragma unroll
        for (int off = 4; off <= 32; off <<= 1) {       // reduce over grp bits
            #pragma unroll
            for (int k = 0; k < 8; ++k) acc[k] += __shfl_xor(acc[k], off);
            zs += __shfl_xor(zs, off);
        }
        if (grp == 0) {
            float lz = __logf(zs);
            #pragma unroll
            for (int k = 0; k < 8; ++k)
                lds_out[bq * 8 + k][wv * 4 + r] = __logf(acc[k]) - lz;
        }
    }
    __syncthreads();
    if (threadIdx.x < 128) {
        int bl = threadIdx.x >> 2, ch = threadIdx.x & 3;
        float4 v = make_float4(lds_out[bl][ch * 4 + 0], lds_out[bl][ch * 4 + 1],
                               lds_out[bl][ch * 4 + 2], lds_out[bl][ch * 4 + 3]);
        *reinterpret_cast<float4*>(
            out + (size_t)(g * GB + bl) * NN + n0 + ch * 4) = v;
    }
}

// ---------------------------------------------------------------------------
extern "C" void kernel_launch(void* const* d_in, const int* in_sizes, int n_in,
                              void* d_out, int out_size, void* d_ws, size_t ws_size,
                              hipStream_t stream) {
    const float* child_ll = (const float*)d_in[0];   // [B, C]
    const float* log_w    = (const float*)d_in[1];   // [NSE]
    const int*   rows     = (const int*)  d_in[2];   // [NSE] sorted
    const int*   cols     = (const int*)  d_in[3];   // [NSE]
    float* out = (float*)d_out;                      // [B, N]

    // ws: [0,6MiB) cw (uint2 x (NSE+64)) | [6MiB,+33KB) rs | [8MiB,24MiB) cet
    char* ws = (char*)d_ws;
    uint2*        cwp = (uint2*)ws;
    int*          rs  = (int*)(ws + (size_t)6 * 1024 * 1024);
    unsigned int* cet = (unsigned int*)(ws + (size_t)8 * 1024 * 1024);

    prep_cw_kernel<<<(NSE_ + 64 + 255) / 256, 256, 0, stream>>>(
        log_w, rows, cols, cwp, rs);
    transpose_kernel<<<(CC / 64) * 8, 256, 0, stream>>>(child_ll, cet);
    sum_rows_kernel<<<(NN / 16) * 8, 256, 0, stream>>>(
        cwp, rs, (const uint4*)cet, out);
}

// Round 4
// 131.949 us; speedup vs baseline: 1.3215x; 1.0264x over previous
//
#include <hip/hip_runtime.h>
#include <hip/hip_bf16.h>

// B=256 batch, N=8192 rows, C=32768 cols, NSE=524288 edges (rows sorted,
// every row present at least once).
#define BB   256
#define NN   8192
#define CC   32768
#define NSE_ 524288
#define GB   32                          // batches per XCD group (8 groups)
#define PREP_BLOCKS ((NSE_ + 64 + 255) / 256)   // 2049
#define TP_TILE 128
#define TP_BLOCKS ((CC / TP_TILE) * 8)          // 2048

typedef float v2f __attribute__((ext_vector_type(2)));

__device__ __forceinline__ unsigned int f2bf_rne(float f) {
    unsigned int u = __float_as_uint(f);
    return (u + 0x7fffu + ((u >> 16) & 1u)) >> 16;   // round-to-nearest-even
}

// ---------------------------------------------------------------------------
// Fused prep + transpose (independent halves of one grid):
//  blocks [0, PREP_BLOCKS): cw[e] = (col, exp(log_w)) uint2, 64 zero pads,
//                           CSR row_start from sorted rows.
//  blocks [PREP_BLOCKS, +TP_BLOCKS): cet[g][c][bl] = bf16(exp(ll[g*32+bl][c]))
//    layout [8][CC][32] bf16. float4 reads (1KB/wave-instr), 8KB contiguous
//    bf16 writes per block.
// ---------------------------------------------------------------------------
__global__ __launch_bounds__(256) void prep_transpose_kernel(
    const float* __restrict__ lw, const int* __restrict__ rows,
    const int* __restrict__ cols, const float* __restrict__ ll,
    uint2* __restrict__ cw, int* __restrict__ rs,
    unsigned int* __restrict__ cet32) {
    int bid = blockIdx.x;
    int t = threadIdx.x;
    if (bid < PREP_BLOCKS) {
        int e = bid * 256 + t;
        if (e < NSE_) {
            cw[e] = make_uint2((unsigned)cols[e],
                               __float_as_uint(__expf(lw[e])));
            if (e == 0) { rs[0] = 0; rs[NN] = NSE_; }
            else if (rows[e] != rows[e - 1]) rs[rows[e]] = e;
        } else if (e < NSE_ + 64) {
            cw[e] = make_uint2(0u, 0u);     // col=0 (safe), w=0
        }
        return;
    }
    bid -= PREP_BLOCKS;
    int g = bid & 7;
    int ct = bid >> 3;
    int c0 = ct * TP_TILE, b0 = g * GB;
    __shared__ float tile[TP_TILE][GB + 1];   // [c_local][b_local], ~16.9KB
    #pragma unroll
    for (int k = 0; k < 4; ++k) {
        int idx = t + 256 * k;          // 0..1023
        int bl = idx >> 5;              // 0..31
        int c4 = idx & 31;              // float4 slot along C
        const float4 v = *reinterpret_cast<const float4*>(
            ll + (size_t)(b0 + bl) * CC + c0 + c4 * 4);
        tile[c4 * 4 + 0][bl] = v.x;
        tile[c4 * 4 + 1][bl] = v.y;
        tile[c4 * 4 + 2][bl] = v.z;
        tile[c4 * 4 + 3][bl] = v.w;
    }
    __syncthreads();
    size_t baseu = ((size_t)g * CC + c0) * 16;   // uint index, 2 bf16/uint
    #pragma unroll
    for (int k = 0; k < 8; ++k) {
        int u = t + 256 * k;            // 0..2047
        int c = u >> 4, b2 = (u & 15) * 2;
        unsigned int lo = f2bf_rne(__expf(tile[c][b2]));
        unsigned int hi = f2bf_rne(__expf(tile[c][b2 + 1]));
        cet32[baseu + u] = lo | (hi << 16);
    }
}

// ---------------------------------------------------------------------------
// Main gather-accumulate. Block = (16-row tile, g). 4 waves x 4 rows each.
// Lane = (grp = lane>>2 edge slot 0..15, bq = lane&3 batch octet).
// Full 64-edge chunks run unpredicated; only the tail chunk masks w by e<t.
// v2f accumulators -> v_pk_fma_f32. Epilogue: shfl_xor reduce over grp,
// LDS-stage 16x32 outputs, coalesced float4 stores.
// ---------------------------------------------------------------------------
__global__ __launch_bounds__(256) void sum_rows_kernel(
    const uint2* __restrict__ cw, const int* __restrict__ rs,
    const uint4* __restrict__ cet, float* __restrict__ out) {
    __shared__ float lds_out[32][17];
    int g = blockIdx.x & 7;             // -> XCD round-robin
    int ntile = blockIdx.x >> 3;
    int n0 = ntile * 16;
    int wv = threadIdx.x >> 6;
    int lane = threadIdx.x & 63;
    int grp = lane >> 2;                // 0..15 edge slot
    int bq = lane & 3;                  // 0..3 batch octet
    const uint4* slice = cet + (size_t)g * CC * 4;   // 4 uint4 per col

    for (int r = 0; r < 4; ++r) {
        int n = n0 + wv * 4 + r;
        int s = __builtin_amdgcn_readfirstlane(rs[n]);
        int t = __builtin_amdgcn_readfirstlane(rs[n + 1]);
        v2f acc[4];
        acc[0] = 0.f; acc[1] = 0.f; acc[2] = 0.f; acc[3] = 0.f;
        float zs = 0.f;
        int eb = s;
        // full chunks: no predication
        for (; eb + 64 <= t; eb += 64) {
            #pragma unroll
            for (int j = 0; j < 4; ++j) {
                uint2 p = cw[eb + j * 16 + grp];
                float w = __uint_as_float(p.y);
                uint4 u = slice[(p.x << 2) | bq];
                v2f w2; w2.x = w; w2.y = w;
                v2f g0, g1, g2, g3;
                g0.x = __uint_as_float(u.x << 16);
                g0.y = __uint_as_float(u.x & 0xffff0000u);
                g1.x = __uint_as_float(u.y << 16);
                g1.y = __uint_as_float(u.y & 0xffff0000u);
                g2.x = __uint_as_float(u.z << 16);
                g2.y = __uint_as_float(u.z & 0xffff0000u);
                g3.x = __uint_as_float(u.w << 16);
                g3.y = __uint_as_float(u.w & 0xffff0000u);
                acc[0] += w2 * g0;
                acc[1] += w2 * g1;
                acc[2] += w2 * g2;
                acc[3] += w2 * g3;
                zs += w;
            }
        }
        // tail chunk: mask weights beyond t (cw padded 64 -> loads safe)
        if (eb < t) {
            #pragma unroll
            for (int j = 0; j < 4; ++j) {
                int e = eb + j * 16 + grp;
                uint2 p = cw[e];
                float w = (e < t) ? __uint_as_float(p.y) : 0.f;
                uint4 u = slice[(p.x << 2) | bq];
                v2f w2; w2.x = w; w2.y = w;
                v2f g0, g1, g2, g3;
                g0.x = __uint_as_float(u.x << 16);
                g0.y = __uint_as_float(u.x & 0xffff0000u);
                g1.x = __uint_as_float(u.y << 16);
                g1.y = __uint_as_float(u.y & 0xffff0000u);
                g2.x = __uint_as_float(u.z << 16);
                g2.y = __uint_as_float(u.z & 0xffff0000u);
                g3.x = __uint_as_float(u.w << 16);
                g3.y = __uint_as_float(u.w & 0xffff0000u);
                acc[0] += w2 * g0;
                acc[1] += w2 * g1;
                acc[2] += w2 * g2;
                acc[3] += w2 * g3;
                zs += w;
            }
        }
        #pragma unroll
        for (int off = 4; off <= 32; off <<= 1) {   // reduce over grp bits
            #pragma unroll
            for (int k = 0; k < 4; ++k) {
                acc[k].x += __shfl_xor(acc[k].x, off);
                acc[k].y += __shfl_xor(acc[k].y, off);
            }
            zs += __shfl_xor(zs, off);
        }
        if (grp == 0) {
            float lz = __logf(zs);
            #pragma unroll
            for (int k = 0; k < 4; ++k) {
                lds_out[bq * 8 + k * 2 + 0][wv * 4 + r] = __logf(acc[k].x) - lz;
                lds_out[bq * 8 + k * 2 + 1][wv * 4 + r] = __logf(acc[k].y) - lz;
            }
        }
    }
    __syncthreads();
    if (threadIdx.x < 128) {
        int bl = threadIdx.x >> 2, ch = threadIdx.x & 3;
        float4 v = make_float4(lds_out[bl][ch * 4 + 0], lds_out[bl][ch * 4 + 1],
                               lds_out[bl][ch * 4 + 2], lds_out[bl][ch * 4 + 3]);
        *reinterpret_cast<float4*>(
            out + (size_t)(g * GB + bl) * NN + n0 + ch * 4) = v;
    }
}

// ---------------------------------------------------------------------------
extern "C" void kernel_launch(void* const* d_in, const int* in_sizes, int n_in,
                              void* d_out, int out_size, void* d_ws, size_t ws_size,
                              hipStream_t stream) {
    const float* child_ll = (const float*)d_in[0];   // [B, C]
    const float* log_w    = (const float*)d_in[1];   // [NSE]
    const int*   rows     = (const int*)  d_in[2];   // [NSE] sorted
    const int*   cols     = (const int*)  d_in[3];   // [NSE]
    float* out = (float*)d_out;                      // [B, N]

    // ws: [0,6MiB) cw uint2[NSE+64] | [6MiB,+33KB) rs | [8MiB,24MiB) cet bf16
    char* ws = (char*)d_ws;
    uint2*        cwp = (uint2*)ws;
    int*          rs  = (int*)(ws + (size_t)6 * 1024 * 1024);
    unsigned int* cet = (unsigned int*)(ws + (size_t)8 * 1024 * 1024);

    prep_transpose_kernel<<<PREP_BLOCKS + TP_BLOCKS, 256, 0, stream>>>(
        log_w, rows, cols, child_ll, cwp, rs, cet);
    sum_rows_kernel<<<(NN / 16) * 8, 256, 0, stream>>>(
        cwp, rs, (const uint4*)cet, out);
}

// Round 5
// 128.088 us; speedup vs baseline: 1.3614x; 1.0301x over previous
//
#include <hip/hip_runtime.h>
#include <hip/hip_bf16.h>

// B=256 batch, N=8192 rows, C=32768 cols, NSE=524288 edges (rows sorted,
// every row present at least once).
#define BB   256
#define NN   8192
#define CC   32768
#define NSE_ 524288
#define GB   32                                 // batches per XCD group
#define PREP_BLOCKS ((NSE_ + 64 + 255) / 256)   // 2049
#define TP_BLOCKS   ((CC / 64) * 8)             // 4096

typedef float v2f __attribute__((ext_vector_type(2)));

__device__ __forceinline__ unsigned int f2bf_rne(float f) {
    unsigned int u = __float_as_uint(f);
    return (u + 0x7fffu + ((u >> 16) & 1u)) >> 16;   // round-to-nearest-even
}
__device__ __forceinline__ unsigned int pack2bf(float lo, float hi) {
    return f2bf_rne(lo) | (f2bf_rne(hi) << 16);
}

// ---------------------------------------------------------------------------
// Fused prep + transpose.
//  blocks [0, PREP_BLOCKS): cw[e] = (col, exp(log_w)) uint2 (+64 zero pads),
//                           CSR row_start from sorted rows.
//  blocks [PREP_BLOCKS, +TP_BLOCKS): one (64-col, g) tile:
//    cet[g][c][bl] = bf16(exp(ll[g*32+bl][c])), layout [8][CC][32] bf16.
//    Pack bf16 pairs BEFORE LDS (uint tile), ds_write_b128 stores,
//    contiguous 1KB/wave global writes.
// ---------------------------------------------------------------------------
__global__ __launch_bounds__(256) void prep_transpose_kernel(
    const float* __restrict__ lw, const int* __restrict__ rows,
    const int* __restrict__ cols, const float* __restrict__ ll,
    uint2* __restrict__ cw, int* __restrict__ rs,
    unsigned int* __restrict__ cet32) {
    int bid = blockIdx.x;
    int t = threadIdx.x;
    if (bid < PREP_BLOCKS) {
        int e = bid * 256 + t;
        if (e < NSE_) {
            cw[e] = make_uint2((unsigned)cols[e],
                               __float_as_uint(__expf(lw[e])));
            if (e == 0) { rs[0] = 0; rs[NN] = NSE_; }
            else if (rows[e] != rows[e - 1]) rs[rows[e]] = e;
        } else if (e < NSE_ + 64) {
            cw[e] = make_uint2(0u, 0u);     // col=0 (safe), w=0
        }
        return;
    }
    bid -= PREP_BLOCKS;
    int g = bid & 7;
    int ct = bid >> 3;
    int c0 = ct * 64, b0 = g * GB;
    // tile_u[bp][c]: packed bf16 pair (batches 2bp, 2bp+1) for local col c
    __shared__ unsigned int tile_u[16][68];
    {
        int c4 = t & 15, bp = t >> 4;       // c4: float4 slot, bp: batch pair
        const float4 fa = *reinterpret_cast<const float4*>(
            ll + (size_t)(b0 + 2 * bp + 0) * CC + c0 + 4 * c4);
        const float4 fb = *reinterpret_cast<const float4*>(
            ll + (size_t)(b0 + 2 * bp + 1) * CC + c0 + 4 * c4);
        uint4 u;
        u.x = pack2bf(__expf(fa.x), __expf(fb.x));
        u.y = pack2bf(__expf(fa.y), __expf(fb.y));
        u.z = pack2bf(__expf(fa.z), __expf(fb.z));
        u.w = pack2bf(__expf(fa.w), __expf(fb.w));
        *reinterpret_cast<uint4*>(&tile_u[bp][4 * c4]) = u;
    }
    __syncthreads();
    {
        int c = t >> 2, q = t & 3;
        uint4 o;
        o.x = tile_u[4 * q + 0][c];
        o.y = tile_u[4 * q + 1][c];
        o.z = tile_u[4 * q + 2][c];
        o.w = tile_u[4 * q + 3][c];
        size_t base_u = ((size_t)g * CC + c0) * 16;
        *reinterpret_cast<uint4*>(cet32 + base_u + c * 16 + 4 * q) = o;
    }
}

// ---------------------------------------------------------------------------
// Main gather-accumulate. Block = (16-row tile, g). 4 waves x 4 rows each.
// Lane = (grp = lane>>2 edge slot 0..15, bq = lane&3 batch octet).
// Per 64-edge chunk: ONE coalesced uint2/lane cw load (512B) staged in
// wave-private LDS (broadcast reads cost no TA lane-slots), next-chunk cw
// prefetched; 4 uint4 gathers (16 edges x one 64B line / 4 lanes each) from
// this XCD's 2 MiB L2-resident slice. Tail edges masked w=0 at stage time.
// Epilogue: shfl_xor reduce over grp, LDS-staged coalesced float4 stores.
// ---------------------------------------------------------------------------
__global__ __launch_bounds__(256) void sum_rows_kernel(
    const uint2* __restrict__ cw, const int* __restrict__ rs,
    const uint4* __restrict__ cet, float* __restrict__ out) {
    __shared__ uint2 stage[4][64];
    __shared__ float lds_out[32][17];
    int g = blockIdx.x & 7;             // -> XCD round-robin
    int ntile = blockIdx.x >> 3;
    int n0 = ntile * 16;
    int wv = threadIdx.x >> 6;
    int lane = threadIdx.x & 63;
    int grp = lane >> 2;                // 0..15 edge slot
    int bq = lane & 3;                  // 0..3 batch octet
    const uint4* slice = cet + (size_t)g * CC * 4;   // 4 uint4 per col
    uint2* st = stage[wv];

    for (int r = 0; r < 4; ++r) {
        int n = n0 + wv * 4 + r;
        int s = __builtin_amdgcn_readfirstlane(rs[n]);
        int t = __builtin_amdgcn_readfirstlane(rs[n + 1]);
        v2f acc[4];
        acc[0] = 0.f; acc[1] = 0.f; acc[2] = 0.f; acc[3] = 0.f;
        float zs = 0.f;
        uint2 v = cw[s + lane];                     // first chunk (pad-safe)
        for (int eb = s; eb < t; eb += 64) {
            if (eb + lane >= t) v.y = 0u;           // mask foreign/pad edges
            st[lane] = v;                           // wave-private, no barrier
            if (eb + 64 < t) v = cw[eb + 64 + lane];   // prefetch next chunk
            #pragma unroll
            for (int j = 0; j < 4; ++j) {
                uint2 p = st[j * 16 + grp];         // LDS broadcast
                float w = __uint_as_float(p.y);
                uint4 u = slice[(p.x << 2) | bq];   // one 64B line / 4 lanes
                v2f w2; w2.x = w; w2.y = w;
                v2f g0, g1, g2, g3;
                g0.x = __uint_as_float(u.x << 16);
                g0.y = __uint_as_float(u.x & 0xffff0000u);
                g1.x = __uint_as_float(u.y << 16);
                g1.y = __uint_as_float(u.y & 0xffff0000u);
                g2.x = __uint_as_float(u.z << 16);
                g2.y = __uint_as_float(u.z & 0xffff0000u);
                g3.x = __uint_as_float(u.w << 16);
                g3.y = __uint_as_float(u.w & 0xffff0000u);
                acc[0] += w2 * g0;
                acc[1] += w2 * g1;
                acc[2] += w2 * g2;
                acc[3] += w2 * g3;
                zs += w;
            }
        }
        #pragma unroll
        for (int off = 4; off <= 32; off <<= 1) {   // reduce over grp bits
            #pragma unroll
            for (int k = 0; k < 4; ++k) {
                acc[k].x += __shfl_xor(acc[k].x, off);
                acc[k].y += __shfl_xor(acc[k].y, off);
            }
            zs += __shfl_xor(zs, off);
        }
        if (grp == 0) {
            float lz = __logf(zs);
            #pragma unroll
            for (int k = 0; k < 4; ++k) {
                lds_out[bq * 8 + k * 2 + 0][wv * 4 + r] = __logf(acc[k].x) - lz;
                lds_out[bq * 8 + k * 2 + 1][wv * 4 + r] = __logf(acc[k].y) - lz;
            }
        }
    }
    __syncthreads();
    if (threadIdx.x < 128) {
        int bl = threadIdx.x >> 2, ch = threadIdx.x & 3;
        float4 v = make_float4(lds_out[bl][ch * 4 + 0], lds_out[bl][ch * 4 + 1],
                               lds_out[bl][ch * 4 + 2], lds_out[bl][ch * 4 + 3]);
        *reinterpret_cast<float4*>(
            out + (size_t)(g * GB + bl) * NN + n0 + ch * 4) = v;
    }
}

// ---------------------------------------------------------------------------
extern "C" void kernel_launch(void* const* d_in, const int* in_sizes, int n_in,
                              void* d_out, int out_size, void* d_ws, size_t ws_size,
                              hipStream_t stream) {
    const float* child_ll = (const float*)d_in[0];   // [B, C]
    const float* log_w    = (const float*)d_in[1];   // [NSE]
    const int*   rows     = (const int*)  d_in[2];   // [NSE] sorted
    const int*   cols     = (const int*)  d_in[3];   // [NSE]
    float* out = (float*)d_out;                      // [B, N]

    // ws: [0,6MiB) cw uint2[NSE+64] | [6MiB,+33KB) rs | [8MiB,24MiB) cet bf16
    char* ws = (char*)d_ws;
    uint2*        cwp = (uint2*)ws;
    int*          rs  = (int*)(ws + (size_t)6 * 1024 * 1024);
    unsigned int* cet = (unsigned int*)(ws + (size_t)8 * 1024 * 1024);

    prep_transpose_kernel<<<PREP_BLOCKS + TP_BLOCKS, 256, 0, stream>>>(
        log_w, rows, cols, child_ll, cwp, rs, cet);
    sum_rows_kernel<<<(NN / 16) * 8, 256, 0, stream>>>(
        cwp, rs, (const uint4*)cet, out);
}